// Round 10
// baseline (99.704 us; speedup 1.0000x reference)
//
#include <hip/hip_runtime.h>
#include <cfloat>

#define K_CODES 256
#define D_DIM 5
#define T_DIM 16384
#define B_DIM 32
#define NPTS (B_DIM * T_DIM)     // 524288 points
#define NELEM (NPTS * D_DIM)     // 2621440 elements
#define PPT 2                    // one point-pair per thread
#define BLK 256
#define NBLOCKS (NPTS / (PPT * BLK))  // 1024 blocks: 4/CU, 16 waves/CU

typedef float f2 __attribute__((ext_vector_type(2)));  // -> v_pk_*_f32

__global__ __launch_bounds__(BLK) void vq_main(const float* __restrict__ x,
                                               const float* __restrict__ e,
                                               float* __restrict__ out,
                                               double* __restrict__ partials) {
    // ---- per-block codebook prep into LDS (np-exact esq) ----
    __shared__ float4 cbA[K_CODES];                 // c0..c3
    __shared__ __align__(16) float2 cbB[K_CODES];   // c4, esq
    {
        int k = threadIdx.x;  // BLK == K_CODES
        float v0 = e[0 * K_CODES + k];
        float v1 = e[1 * K_CODES + k];
        float v2 = e[2 * K_CODES + k];
        float v3 = e[3 * K_CODES + k];
        float v4 = e[4 * K_CODES + k];
        // np: e**2 rounds each square, then sequential ascending adds (no fma)
        float esq = __fmul_rn(v0, v0);
        esq = __fadd_rn(esq, __fmul_rn(v1, v1));
        esq = __fadd_rn(esq, __fmul_rn(v2, v2));
        esq = __fadd_rn(esq, __fmul_rn(v3, v3));
        esq = __fadd_rn(esq, __fmul_rn(v4, v4));
        cbA[k] = make_float4(v0, v1, v2, v3);
        cbB[k] = make_float2(v4, esq);
    }
    __syncthreads();

    // ---- load this thread's point-pair (coalesced float2 per d) ----
    const int g = blockIdx.x * BLK + threadIdx.x;
    const int p0 = g * PPT;
    const int b = p0 >> 14;            // p0 / T_DIM
    const int t = p0 & (T_DIM - 1);    // p0 % T_DIM (multiple of 2)
    const float* xp = x + (b * D_DIM) * T_DIM + t;

    f2 xv[D_DIM];
    #pragma unroll
    for (int d = 0; d < D_DIM; d++) {
        float2 v = *(const float2*)(xp + d * T_DIM);
        xv[d] = (f2){v.x, v.y};
    }
    // np: x**2 rounds each square, then sequential ascending adds (no fma).
    // Packed mul/add are IEEE-RN per lane-half == __fmul_rn/__fadd_rn.
    f2 xsq = xv[0] * xv[0];
    xsq = xsq + xv[1] * xv[1];
    xsq = xsq + xv[2] * xv[2];
    xsq = xsq + xv[3] * xv[3];
    xsq = xsq + xv[4] * xv[4];

    float best0 = FLT_MAX, best1 = FLT_MAX;
    int bidx0 = 0, bidx1 = 0;

    // ---- scan, k stepped by 2 so one b128 covers cbB[k],cbB[k+1] ----
    // Per element: dot = rnd-mul then 4 RN-fma (sgemm chain); dist =
    // (xsq - (dot+dot)) + esq left-to-right — numpy-exact. strict < ascending
    // k = np first-min tie-break. Uniform LDS address -> broadcast, no conflict.
    #pragma unroll 4
    for (int k = 0; k < K_CODES; k += 2) {
        float4 cA0 = cbA[k];
        float4 cA1 = cbA[k + 1];
        float4 cBp = *(const float4*)&cbB[k];   // (c4_k, esq_k, c4_k1, esq_k1)
        #pragma unroll
        for (int kk = 0; kk < 2; kk++) {
            float4 cA = kk ? cA1 : cA0;
            f2 c0 = {cA.x, cA.x}, c1 = {cA.y, cA.y}, c2 = {cA.z, cA.z},
               c3 = {cA.w, cA.w};
            f2 c4 = kk ? (f2){cBp.z, cBp.z} : (f2){cBp.x, cBp.x};
            f2 es = kk ? (f2){cBp.w, cBp.w} : (f2){cBp.y, cBp.y};
            f2 dot = xv[0] * c0;                              // v_pk_mul_f32
            dot = __builtin_elementwise_fma(xv[1], c1, dot);  // v_pk_fma_f32
            dot = __builtin_elementwise_fma(xv[2], c2, dot);
            dot = __builtin_elementwise_fma(xv[3], c3, dot);
            dot = __builtin_elementwise_fma(xv[4], c4, dot);
            f2 dist = (xsq - (dot + dot)) + es;               // pk sub/add
            int ki = k + kk;
            if (dist.x < best0) { best0 = dist.x; bidx0 = ki; }
            if (dist.y < best1) { best1 = dist.y; bidx1 = ki; }
        }
    }

    // ---- gather selected codewords, coalesced float2 stores; local loss ----
    float4 g0A = cbA[bidx0];
    float2 g0B = cbB[bidx0];
    float4 g1A = cbA[bidx1];
    float2 g1B = cbB[bidx1];
    float q0[D_DIM] = {g0A.x, g0A.y, g0A.z, g0A.w, g0B.x};
    float q1[D_DIM] = {g1A.x, g1A.y, g1A.z, g1A.w, g1B.x};

    float ls = 0.f;
    float* op = out + (b * D_DIM) * T_DIM + t;
    #pragma unroll
    for (int d = 0; d < D_DIM; d++) {
        float2 o = make_float2(q0[d], q1[d]);
        *(float2*)(op + d * T_DIM) = o;       // straight-through output == q
        float df0 = xv[d].x - q0[d];
        float df1 = xv[d].y - q1[d];
        ls += df0 * df0 + df1 * df1;
    }

    // ---- block loss reduction -> one slot per block (no atomics/init) ----
    #pragma unroll
    for (int off = 32; off > 0; off >>= 1) ls += __shfl_down(ls, off, 64);
    __shared__ float wsum[BLK / 64];
    int lane = threadIdx.x & 63;
    int wid = threadIdx.x >> 6;
    if (lane == 0) wsum[wid] = ls;
    __syncthreads();
    if (threadIdx.x == 0) {
        float tot = 0.f;
        #pragma unroll
        for (int w = 0; w < BLK / 64; w++) tot += wsum[w];
        partials[blockIdx.x] = (double)tot;  // slot overwritten every launch
    }
}

__global__ __launch_bounds__(1024) void vq_finalize(
        const double* __restrict__ partials, float* __restrict__ out) {
    double v = partials[threadIdx.x];   // 1024 threads, one slot each
    #pragma unroll
    for (int off = 32; off > 0; off >>= 1) v += __shfl_down(v, off, 64);
    __shared__ double wsum[1024 / 64];
    int lane = threadIdx.x & 63;
    int wid = threadIdx.x >> 6;
    if (lane == 0) wsum[wid] = v;
    __syncthreads();
    if (threadIdx.x == 0) {
        double tot = 0.0;
        #pragma unroll
        for (int w = 0; w < 1024 / 64; w++) tot += wsum[w];
        float loss = (float)(tot / (double)NELEM);
        out[NELEM] = loss;      // dictionary_loss
        out[NELEM + 1] = loss;  // commitment_loss (identical forward value)
    }
}

extern "C" void kernel_launch(void* const* d_in, const int* in_sizes, int n_in,
                              void* d_out, int out_size, void* d_ws, size_t ws_size,
                              hipStream_t stream) {
    const float* x = (const float*)d_in[0];   // fp32 (B,D,T)
    const float* e = (const float*)d_in[1];   // fp32 (D,K)
    float* out = (float*)d_out;               // fp32: quantized + 2 losses
    double* partials = (double*)d_ws;         // 1024 × 8 B

    vq_main<<<NBLOCKS, BLK, 0, stream>>>(x, e, out, partials);
    vq_finalize<<<1, NBLOCKS, 0, stream>>>(partials, out);
}